// Round 2
// baseline (69.070 us; speedup 1.0000x reference)
//
#include <hip/hip_runtime.h>
#include <hip/hip_cooperative_groups.h>
#include <cmath>

#define NPTS 12288
#define NB   4
#define MB   3072      // points per batch
#define DF   128
#define TAUF 0.1f
#define NI   24        // i-points per block (4 waves x 6 points)
#define INVALID_PK 0x00FFFFFFu

static __device__ __forceinline__ unsigned sad_u8(unsigned a, unsigned b) {
#if __has_builtin(__builtin_amdgcn_sad_u8)
    return __builtin_amdgcn_sad_u8(a, b, 0u);
#else
    unsigned d, z = 0u;
    asm("v_sad_u8 %0, %1, %2, %3" : "=v"(d) : "v"(a), "v"(b), "v"(z));
    return d;
#endif
}

// One cooperative kernel: phase A (logits+validity) -> grid sync -> phase B (scan+outputs)
__global__ __launch_bounds__(256) void k_fused(
    const float* __restrict__ feats, const float* __restrict__ W,
    const float* __restrict__ bias, const int* __restrict__ coords,
    float* __restrict__ out_logits, float* __restrict__ out_peaks,
    float* __restrict__ out_mean,
    unsigned* __restrict__ pts_pk, float* __restrict__ pts_h)
{
    __shared__ unsigned s_pk[MB];             // 12 KB
    __shared__ float    s_h[MB];              // 12 KB
    const int tid   = threadIdx.x;
    const int wave  = tid >> 6, lane = tid & 63;
    const int iBase = blockIdx.x * NI;        // 3072 % 24 == 0 -> block stays in one batch
    const int batch = iBase / MB;
    const int bBase = batch * MB;
    const int i0    = iBase + wave * 6;       // this wave's 6 consecutive points

    // ---------------- phase A: logits + heat + validity for own 6 rows ----------------
    const float2 w2 = ((const float2*)W)[lane];
    const float  bv = bias[0];

    unsigned pip[6];
    float    ph[6];
    #pragma unroll
    for (int q = 0; q < 6; ++q) {
        const int row = i0 + q;
        const float2 f = ((const float2*)(feats + (size_t)row * DF))[lane];
        float s = f.x * w2.x + f.y * w2.y;        // identical accumulation order to baseline
        #pragma unroll
        for (int off = 32; off; off >>= 1) s += __shfl_xor(s, off);
        const float logit = s + bv;
        const float heat  = 1.0f / (1.0f + expf(-logit));
        const bool  valid = heat > TAUF;
        const int4  c = ((const int4*)coords)[row];   // (batch, x, y, z) -- broadcast load
        pip[q] = valid ? ((unsigned)c.y | ((unsigned)c.z << 8) | ((unsigned)c.w << 16))
                       : INVALID_PK;
        ph[q]  = valid ? heat : -INFINITY;
        if (lane == 0) {
            out_logits[row] = logit;
            pts_pk[row] = pip[q];
            pts_h[row]  = ph[q];
        }
    }

    cooperative_groups::this_grid().sync();   // publish pk/heat grid-wide

    // ---------------- phase B: stage batch -> scan -> outputs (baseline body) ----------------
    {   // vectorized stage: 3 + 3 uint4 per thread
        uint4* d1 = (uint4*)s_pk;  const uint4* g1 = (const uint4*)(pts_pk + bBase);
        uint4* d2 = (uint4*)s_h;   const uint4* g2 = (const uint4*)(pts_h  + bBase);
        #pragma unroll
        for (int k = 0; k < MB / 4 / 256; ++k) {
            d1[tid + k * 256] = g1[tid + k * 256];
            d2[tid + k * 256] = g2[tid + k * 256];
        }
    }
    __syncthreads();

    unsigned mmlo[6], mmhi[6];
    #pragma unroll
    for (int q = 0; q < 6; ++q) { mmlo[q] = 0u; mmhi[q] = 0u; }

    // ---- pair scan: 1 ds_read_b32 + {sad,cmp,cndmask,or} x6 per tile ----
    #pragma unroll
    for (int t = 0; t < 32; ++t) {
        const unsigned pj = s_pk[t * 64 + lane];
        #pragma unroll
        for (int q = 0; q < 6; ++q) {
            const bool cc = sad_u8(pip[q], pj) <= 1u;    // manhattan<=1 <=> d2<=1.21
            mmlo[q] |= cc ? (1u << t) : 0u;
        }
    }
    #pragma unroll
    for (int t = 32; t < 48; ++t) {
        const unsigned pj = s_pk[t * 64 + lane];
        #pragma unroll
        for (int q = 0; q < 6; ++q) {
            const bool cc = sad_u8(pip[q], pj) <= 1u;
            mmhi[q] |= cc ? (1u << (t - 32)) : 0u;
        }
    }

    // ---- per-point epilogue: nm from mask, then outputs ----
    #pragma unroll
    for (int q = 0; q < 6; ++q) {
        const int i = i0 + q;
        const unsigned long long mm = (unsigned long long)mmlo[q]
                                    | ((unsigned long long)mmhi[q] << 32);
        const bool validi = (pip[q] != INVALID_PK);       // wave-uniform
        float nm = -INFINITY;
        int   cnt = 0;
        if (validi) {                                     // invalid i: mask is dense garbage, skip
            unsigned long long bal = __ballot(mm != 0ull);
            while (bal) {
                const int sl = __builtin_ctzll(bal);
                bal &= bal - 1;
                unsigned long long m2 = __shfl(mm, sl);
                cnt += __popcll(m2);
                while (m2) {
                    const int t = __builtin_ctzll(m2);
                    m2 &= m2 - 1;
                    nm = fmaxf(nm, s_h[t * 64 + sl]);     // broadcast read, conflict-free
                }
            }
        }
        const bool is_peak = validi && (ph[q] >= nm);

        if (lane == 0) {
            const float4 pk = is_peak
                ? make_float4((float)batch, (float)(pip[q] & 255u),
                              (float)((pip[q] >> 8) & 255u), (float)(pip[q] >> 16))
                : make_float4(0.f, 0.f, 0.f, 0.f);
            ((float4*)out_peaks)[i] = pk;
        }

        float* om = out_mean + (size_t)i * DF;
        if (is_peak) {
            float a0 = 0.f, a1 = 0.f;
            unsigned long long bal = __ballot(mm != 0ull);
            while (bal) {
                const int sl = __builtin_ctzll(bal);
                bal &= bal - 1;
                unsigned long long m2 = __shfl(mm, sl);
                while (m2) {
                    const int t = __builtin_ctzll(m2);
                    m2 &= m2 - 1;
                    const float* fj = feats + (size_t)(bBase + t * 64 + sl) * DF;
                    a0 += fj[lane];
                    a1 += fj[64 + lane];
                }
            }
            const float fc = (float)cnt;            // cnt >= 1 (self matches)
            om[lane]      = a0 / fc;
            om[64 + lane] = a1 / fc;
        } else {
            om[lane]      = 0.f;                    // non-peak rows are 0
            om[64 + lane] = 0.f;
        }
    }
}

extern "C" void kernel_launch(void* const* d_in, const int* in_sizes, int n_in,
                              void* d_out, int out_size, void* d_ws, size_t ws_size,
                              hipStream_t stream) {
    const float* feats  = (const float*)d_in[0];
    const float* W      = (const float*)d_in[1];
    const float* bias   = (const float*)d_in[2];
    const int*   coords = (const int*)d_in[3];

    float* out        = (float*)d_out;
    float* out_logits = out;               // N
    float* out_peaks  = out + NPTS;        // N*4
    float* out_mean   = out + NPTS * 5;    // N*128

    unsigned* pts_pk = (unsigned*)d_ws;                      // 48 KB
    float*    pts_h  = (float*)((char*)d_ws + 65536);        // 48 KB

    void* args[] = { (void*)&feats, (void*)&W, (void*)&bias, (void*)&coords,
                     (void*)&out_logits, (void*)&out_peaks, (void*)&out_mean,
                     (void*)&pts_pk, (void*)&pts_h };
    hipLaunchCooperativeKernel((const void*)k_fused, dim3(NPTS / NI), dim3(256),
                               args, 0, stream);
}

// Round 3
// 20.004 us; speedup vs baseline: 3.4528x; 3.4528x over previous
//
#include <hip/hip_runtime.h>
#include <cmath>

#define NPTS 12288
#define NB   4
#define MB   3072      // points per batch
#define DF   128
#define TAUF 0.1f
#define NI   24        // i-points per block (4 waves x 6 points)
#define INVALID_PK 0x00FFFFFFu

static __device__ __forceinline__ unsigned sad_u8(unsigned a, unsigned b) {
#if __has_builtin(__builtin_amdgcn_sad_u8)
    return __builtin_amdgcn_sad_u8(a, b, 0u);
#else
    unsigned d, z = 0u;
    asm("v_sad_u8 %0, %1, %2, %3" : "=v"(d) : "v"(a), "v"(b), "v"(z));
    return d;
#endif
}

// ---------------- kernel 1: logits + heat; split pk / heat arrays ----------------
__global__ __launch_bounds__(256) void k_logits(
    const float* __restrict__ feats, const float* __restrict__ W,
    const float* __restrict__ bias, const int* __restrict__ coords,
    float* __restrict__ out_logits, unsigned* __restrict__ pts_pk,
    float* __restrict__ pts_h)
{
    const int gtid = blockIdx.x * 256 + threadIdx.x;
    const int row  = gtid >> 6;
    const int lane = gtid & 63;
    const float2 f = ((const float2*)(feats + (size_t)row * DF))[lane];
    const float2 w = ((const float2*)W)[lane];
    float s = f.x * w.x + f.y * w.y;
    #pragma unroll
    for (int off = 32; off; off >>= 1) s += __shfl_xor(s, off);
    if (lane == 0) {
        const float logit = s + bias[0];
        out_logits[row] = logit;
        const float heat = 1.0f / (1.0f + expf(-logit));
        const bool valid = heat > TAUF;
        const int4 c = ((const int4*)coords)[row];   // (batch, x, y, z)
        pts_pk[row] = valid ? ((unsigned)c.y | ((unsigned)c.z << 8) | ((unsigned)c.w << 16))
                            : INVALID_PK;
        pts_h[row]  = valid ? heat : -INFINITY;
    }
}

// ---------------- kernel 2: sparse-aware scan -> is_peak -> peaks + feat_mean ----------------
__global__ __launch_bounds__(256) void k_main(
    const float* __restrict__ feats, const unsigned* __restrict__ pts_pk,
    const float* __restrict__ pts_h,
    float* __restrict__ out_peaks, float* __restrict__ out_mean)
{
    __shared__ unsigned s_pk[MB];             // 12 KB (pk only; heat served from L2)
    __shared__ unsigned s_vq[4];
    const int tid   = threadIdx.x;
    const int wave  = tid >> 6, lane = tid & 63;
    const int iBase = blockIdx.x * NI;        // 3072 % 24 == 0 -> block stays in one batch
    const int batch = iBase / MB;
    const int bBase = batch * MB;
    const int i0    = iBase + wave * 6;       // this wave's 6 consecutive points

    // own 6 points: pk + heat (broadcast loads), validity bitmask
    unsigned pip[6];
    float    ph[6];
    unsigned vq = 0u;
    #pragma unroll
    for (int q = 0; q < 6; ++q) {
        pip[q] = pts_pk[i0 + q];
        ph[q]  = pts_h[i0 + q];
        if (pip[q] != INVALID_PK) vq |= 1u << q;
    }
    if (lane == 0) s_vq[wave] = vq;
    __syncthreads();
    const unsigned anyv = s_vq[0] | s_vq[1] | s_vq[2] | s_vq[3];

    if (!anyv) {   // ~55-60% of blocks: every point invalid -> all outputs zero
        #pragma unroll
        for (int q = 0; q < 6; ++q) {
            const int i = i0 + q;
            if (lane == 0) ((float4*)out_peaks)[i] = make_float4(0.f, 0.f, 0.f, 0.f);
            ((float2*)(out_mean + (size_t)i * DF))[lane] = make_float2(0.f, 0.f);
        }
        return;
    }

    {   // vectorized stage: 3 uint4 per thread (pk only)
        uint4* d1 = (uint4*)s_pk;  const uint4* g1 = (const uint4*)(pts_pk + bBase);
        #pragma unroll
        for (int k = 0; k < MB / 4 / 256; ++k) d1[tid + k * 256] = g1[tid + k * 256];
    }
    __syncthreads();

    unsigned mmlo[6], mmhi[6];
    #pragma unroll
    for (int q = 0; q < 6; ++q) { mmlo[q] = 0u; mmhi[q] = 0u; }

    if (vq) {   // ~14% of waves: at least one valid point -> run the pair scan
        #pragma unroll
        for (int t = 0; t < 32; ++t) {
            const unsigned pj = s_pk[t * 64 + lane];
            #pragma unroll
            for (int q = 0; q < 6; ++q) {
                const bool cc = sad_u8(pip[q], pj) <= 1u;    // manhattan<=1 <=> d2<=1.21
                mmlo[q] |= cc ? (1u << t) : 0u;
            }
        }
        #pragma unroll
        for (int t = 32; t < 48; ++t) {
            const unsigned pj = s_pk[t * 64 + lane];
            #pragma unroll
            for (int q = 0; q < 6; ++q) {
                const bool cc = sad_u8(pip[q], pj) <= 1u;
                mmhi[q] |= cc ? (1u << (t - 32)) : 0u;
            }
        }
    }

    // ---- per-point epilogue: nm from mask, then outputs ----
    #pragma unroll
    for (int q = 0; q < 6; ++q) {
        const int i = i0 + q;
        const unsigned long long mm = (unsigned long long)mmlo[q]
                                    | ((unsigned long long)mmhi[q] << 32);
        const bool validi = (vq >> q) & 1u;
        float nm = -INFINITY;
        int   cnt = 0;
        if (validi) {                                     // invalid i: mask is garbage, skip
            unsigned long long bal = __ballot(mm != 0ull);
            while (bal) {
                const int sl = __builtin_ctzll(bal);
                bal &= bal - 1;
                unsigned long long m2 = __shfl(mm, sl);
                cnt += __popcll(m2);
                while (m2) {
                    const int t = __builtin_ctzll(m2);
                    m2 &= m2 - 1;
                    nm = fmaxf(nm, pts_h[bBase + t * 64 + sl]);  // rare broadcast read (L2)
                }
            }
        }
        const bool is_peak = validi && (ph[q] >= nm);

        if (lane == 0) {
            const float4 pk = is_peak
                ? make_float4((float)batch, (float)(pip[q] & 255u),
                              (float)((pip[q] >> 8) & 255u), (float)(pip[q] >> 16))
                : make_float4(0.f, 0.f, 0.f, 0.f);
            ((float4*)out_peaks)[i] = pk;
        }

        float* om = out_mean + (size_t)i * DF;
        if (is_peak) {
            float a0 = 0.f, a1 = 0.f;
            unsigned long long bal = __ballot(mm != 0ull);
            while (bal) {
                const int sl = __builtin_ctzll(bal);
                bal &= bal - 1;
                unsigned long long m2 = __shfl(mm, sl);
                while (m2) {
                    const int t = __builtin_ctzll(m2);
                    m2 &= m2 - 1;
                    const float* fj = feats + (size_t)(bBase + t * 64 + sl) * DF;
                    a0 += fj[lane];
                    a1 += fj[64 + lane];
                }
            }
            const float fc = (float)cnt;            // cnt >= 1 (self matches)
            om[lane]      = a0 / fc;
            om[64 + lane] = a1 / fc;
        } else {
            ((float2*)om)[lane] = make_float2(0.f, 0.f);   // full row zero, one store
        }
    }
}

extern "C" void kernel_launch(void* const* d_in, const int* in_sizes, int n_in,
                              void* d_out, int out_size, void* d_ws, size_t ws_size,
                              hipStream_t stream) {
    const float* feats  = (const float*)d_in[0];
    const float* W      = (const float*)d_in[1];
    const float* bias   = (const float*)d_in[2];
    const int*   coords = (const int*)d_in[3];

    float* out        = (float*)d_out;
    float* out_logits = out;               // N
    float* out_peaks  = out + NPTS;        // N*4
    float* out_mean   = out + NPTS * 5;    // N*128

    unsigned* pts_pk = (unsigned*)d_ws;                      // 48 KB
    float*    pts_h  = (float*)((char*)d_ws + 65536);        // 48 KB

    k_logits<<<NPTS / 4, 256, 0, stream>>>(feats, W, bias, coords,
                                           out_logits, pts_pk, pts_h);
    k_main<<<NPTS / NI, 256, 0, stream>>>(feats, pts_pk, pts_h,
                                          out_peaks, out_mean);
}